// Round 16
// baseline (65.155 us; speedup 1.0000x reference)
//
#include <hip/hip_runtime.h>
#include <hip/hip_bf16.h>

// loss = mean((output-target)^2) + ALPHA * sum(masked cosine Gram of
// V[128][196608]), V[f][d] = conv_w[o][i][f][k], d=(site,k), site=(o,i).
//
// Round 16: register-built fragments + tiny LDS frag-exchange.
// Per chunk (8 sites): each wave loads 4 float3 (r9's proven coalesced
// pattern, 192B per 16-lane group), builds its 2 A-fragments in registers
// (r8-validated make_frag, zero slots exact no-ops), publishes them via
// 2 ds_write_b128 into fragbuf[8][64] (8.2KB), barrier, reads 8 B-frags
// back as dense ds_read_b128. conv read exactly once; no transpose
// staging, no /3 magic, no scattered b32 writes. 1024 gram + 2048 mse
// mixed grid (proven r10 recipe), (256,4) -> 16 waves/CU.
// Epilogue/pp/reduce/finalize = r9/r12-validated (1024 tiles, 64-slice).

typedef __attribute__((ext_vector_type(8))) short bf16x8;   // 8 bf16 = 4 VGPR
typedef __attribute__((ext_vector_type(4))) float f32x4;

#define ALPHA 0.0005f
#define TAU 0.2f

#define FDIM 128
#define NGRAM 1024          // gram blocks: 64 sites = 8 chunks of 8
#define NMSE 2048           // mse blocks
#define BLK_FLOATS 24576    // 64 sites * 384 floats
#define NPAIRQ 8192         // packed u32 per partial tile
#define GRAM_ELEMS 16384
#define MSE_N4 2048000      // 8192*1000/4

// branchless RNE f32->bf16 pair pack
__device__ __forceinline__ unsigned int pack_bf2(float lo, float hi) {
    union { float f; unsigned int u; } a, b;
    a.f = lo; b.f = hi;
    unsigned int al = (a.u + 0x7fffu + ((a.u >> 16) & 1u)) >> 16;
    unsigned int bh = (b.u + 0x7fffu + ((b.u >> 16) & 1u)) & 0xffff0000u;
    return (al & 0xffffu) | bh;
}

// fragment: [a.x a.y a.z b.x b.y b.z 0 0] (slots 6,7 zero = exact no-ops;
// same bijection used for A and B so the Gram is unchanged). r8-validated.
__device__ __forceinline__ uint4 make_frag(const float3& a, const float3& b) {
    uint4 r;
    r.x = pack_bf2(a.x, a.y);
    r.y = pack_bf2(a.z, b.x);
    r.z = pack_bf2(b.y, b.z);
    r.w = 0;
    return r;
}

// --------------------------------------------- mixed-role fused kernel
// blocks [0, NGRAM): Gram tile partials. [NGRAM, NGRAM+NMSE): MSE.
__global__ void __launch_bounds__(256, 4) fused_kernel(
        const float* __restrict__ o, const float* __restrict__ t,
        const float* __restrict__ conv,
        float* __restrict__ mse_part, unsigned int* __restrict__ pp) {
    __shared__ uint4 fragbuf[8][64];        // 8.2 KB frag exchange
    __shared__ float red[4];
    const int tid = threadIdx.x;
    const int lane = tid & 63;
    const int wave = tid >> 6;

    if (blockIdx.x >= NGRAM) {
        // ---------------- MSE role ----------------
        const int mb = blockIdx.x - NGRAM;
        const int gid = mb * 256 + tid;
        const f32x4* o4 = reinterpret_cast<const f32x4*>(o);
        const f32x4* t4 = reinterpret_cast<const f32x4*>(t);
        float s = 0.f;
        for (int i = gid; i < MSE_N4; i += NMSE * 256) {
            f32x4 a = o4[i], b = t4[i];
            f32x4 d = a - b;
            s += d[0]*d[0] + d[1]*d[1] + d[2]*d[2] + d[3]*d[3];
        }
        for (int off = 32; off; off >>= 1) s += __shfl_down(s, off);
        if (lane == 0) red[wave] = s;
        __syncthreads();
        if (tid == 0) mse_part[mb] = red[0] + red[1] + red[2] + red[3];
        return;
    }

    // ---------------- Gram role ----------------
    // chunk = 8 sites; K slots: group g -> sites 2g,2g+1 (6 data + 2 zero).
    // Wave w owns output rows [32w, 32w+32) = row-tiles 2w, 2w+1 and is the
    // producer of exactly those two fragments each chunk.
    const int g = lane >> 4;                // lane group 0..3
    const int fl = lane & 15;               // row-within-tile
    // A-load bases: sites 2g, 2g+1; rows 32w+fl and 32w+16+fl
    const float* bp = conv + (size_t)blockIdx.x * BLK_FLOATS;
    const float* pA0s0 = bp + (2 * g) * 384 + (32 * wave + fl) * 3;
    const float* pA0s1 = pA0s0 + 384;
    const float* pA1s0 = bp + (2 * g) * 384 + (32 * wave + 16 + fl) * 3;
    const float* pA1s1 = pA1s0 + 384;

    f32x4 acc0[8], acc1[8];
#pragma unroll
    for (int cc = 0; cc < 8; ++cc) { acc0[cc] = (f32x4)0.f; acc1[cc] = (f32x4)0.f; }

    for (int c = 0; c < 8; ++c) {
        const int co = c * 3072;            // 8 sites per chunk
        const float3 a0s0 = *reinterpret_cast<const float3*>(pA0s0 + co);
        const float3 a0s1 = *reinterpret_cast<const float3*>(pA0s1 + co);
        const float3 a1s0 = *reinterpret_cast<const float3*>(pA1s0 + co);
        const float3 a1s1 = *reinterpret_cast<const float3*>(pA1s1 + co);
        const uint4 fA0 = make_frag(a0s0, a0s1);
        const uint4 fA1 = make_frag(a1s0, a1s1);
        __syncthreads();                    // fragbuf free (prev mfma done)
        fragbuf[2 * wave][lane] = fA0;
        fragbuf[2 * wave + 1][lane] = fA1;
        __syncthreads();                    // all 8 frags published
        const bf16x8 va0 = *reinterpret_cast<const bf16x8*>(&fA0);
        const bf16x8 va1 = *reinterpret_cast<const bf16x8*>(&fA1);
#pragma unroll
        for (int cc = 0; cc < 8; ++cc) {
            const uint4 fb = fragbuf[cc][lane];
            const bf16x8 vb = *reinterpret_cast<const bf16x8*>(&fb);
            acc0[cc] = __builtin_amdgcn_mfma_f32_16x16x32_bf16(va0, vb, acc0[cc], 0, 0, 0);
            acc1[cc] = __builtin_amdgcn_mfma_f32_16x16x32_bf16(va1, vb, acc1[cc], 0, 0, 0);
        }
    }

    // epilogue: bf16-pair-packed partial tile (validated layout):
    // u32[pr*128+col] = pack(G[r0], G[r0+16]), pr = wave*16 + rsub + j,
    // r0 = wave*32 + rsub + j, col = cc*16 + colr.
    unsigned int* myp = pp + (size_t)blockIdx.x * NPAIRQ;
    const int colr = lane & 15;
    const int rsub = (lane >> 4) << 2;
#pragma unroll
    for (int cc = 0; cc < 8; ++cc) {
        const int col = cc * 16 + colr;
#pragma unroll
        for (int j = 0; j < 4; ++j) {
            const int pr = wave * 16 + rsub + j;
            myp[pr * FDIM + col] = pack_bf2(acc0[cc][j], acc1[cc][j]);
        }
    }
}

// ------------------------------------------------- partial reduce (bf16 pairs)
// 512 blocks x 256 thr: block owns 16 packed entries; 16 slices of 64 tiles.
// (r12-validated with 1024 tiles)
__global__ void __launch_bounds__(256) reduce_kernel(
        const unsigned int* __restrict__ pp, float* __restrict__ gram) {
    __shared__ float red[16][16][2];
    const int tid = threadIdx.x;
    const int u = tid & 15;
    const int s = tid >> 4;                 // 0..15
    const int qq = blockIdx.x * 16 + u;
    float lo = 0.f, hi = 0.f;
#pragma unroll 8
    for (int b = s * 64; b < s * 64 + 64; ++b) {
        const unsigned int v = pp[(size_t)b * NPAIRQ + qq];
        lo += __uint_as_float(v << 16);
        hi += __uint_as_float(v & 0xffff0000u);
    }
    red[s][u][0] = lo; red[s][u][1] = hi;
    __syncthreads();
    if (tid < 32) {
        const int u2 = tid >> 1, h = tid & 1;
        float x = 0.f;
#pragma unroll
        for (int s2 = 0; s2 < 16; ++s2) x += red[s2][u2][h];
        gram[(blockIdx.x * 16 + u2) * 2 + h] = x;
    }
}

// ------------------------------------------------------------ finalize
// gram layout: g = (pr*128+col)*2 + h, row = (pr>>4)*32 + (pr&15) + 16h
// (r12/r14-validated, 2048 mse entries)
__global__ void __launch_bounds__(256) finalize_kernel(
        const float* __restrict__ gram, const float* __restrict__ mse_part,
        float* __restrict__ out) {
    __shared__ float rn[FDIM];
    __shared__ float redS[4], redM[4];
    const int tid = threadIdx.x;
    if (tid < FDIM) {
        const int row = tid;
        const int pr = (row >> 5) * 16 + (row & 15);
        const int h = (row >> 4) & 1;
        rn[row] = rsqrtf(gram[(pr * FDIM + row) * 2 + h]);
    }
    __syncthreads();
    float s = 0.f;
    for (int i = tid; i < GRAM_ELEMS; i += 256) {
        const int h = i & 1;
        const int qq = i >> 1;
        const int col = qq & 127;
        const int pr = qq >> 7;
        const int row = (pr >> 4) * 32 + (pr & 15) + (h << 4);
        const float gv = gram[i] * rn[row] * rn[col];
        if (row != col && gv > TAU && gv <= 1.0f) s += gv;
    }
    float m = 0.f;
#pragma unroll 8
    for (int j = 0; j < 8; ++j) m += mse_part[tid * 8 + j];   // 2048 entries
    for (int off = 32; off; off >>= 1) {
        s += __shfl_down(s, off);
        m += __shfl_down(m, off);
    }
    if ((tid & 63) == 0) { redS[tid >> 6] = s; redM[tid >> 6] = m; }
    __syncthreads();
    if (tid == 0)
        out[0] = (redM[0] + redM[1] + redM[2] + redM[3]) * (1.0f / 8192000.0f) +
                 ALPHA * (redS[0] + redS[1] + redS[2] + redS[3]);
}

extern "C" void kernel_launch(void* const* d_in, const int* in_sizes, int n_in,
                              void* d_out, int out_size, void* d_ws, size_t ws_size,
                              hipStream_t stream) {
    const float* output = (const float*)d_in[0];
    const float* target = (const float*)d_in[1];
    const float* conv   = (const float*)d_in[2];
    float* out = (float*)d_out;

    float* wsf       = (float*)d_ws;
    float* mse_part  = wsf;                              // 2048 floats
    float* gram      = wsf + NMSE;                       // 16384 floats
    unsigned int* pp = (unsigned int*)(wsf + NMSE + GRAM_ELEMS); // 33.6 MB
    (void)ws_size;   // need ~33.7 MB; harness provides ~402 MB (r5 profile)

    // all buffers fully written before read -> no memsets
    fused_kernel<<<NGRAM + NMSE, 256, 0, stream>>>(output, target, conv,
                                                   mse_part, pp);
    reduce_kernel<<<NPAIRQ / 16, 256, 0, stream>>>(pp, gram);
    finalize_kernel<<<1, 256, 0, stream>>>(gram, mse_part, out);
}

// Round 17
// 64.220 us; speedup vs baseline: 1.0145x; 1.0145x over previous
//
#include <hip/hip_runtime.h>
#include <hip/hip_bf16.h>

// loss = mean((output-target)^2) + ALPHA * sum(masked cosine Gram of
// V[128][196608]), V[f][d] = conv_w[o][i][f][k], d=(site,k), site=(o,i).
//
// Round 17: r16 + depth-2 cross-barrier load pipeline. r16's inner loop
// drained vmcnt(0) at every __syncthreads (2/chunk) -> per-chunk full
// memory round-trip, convoy across co-resident blocks. Now: chunk c+2's
// 4 float3 loads are issued right after chunk c's registers are consumed
// into fragments, pinned with sched_barrier(0); barriers are raw s_barrier
// with lgkmcnt(0) drains ONLY (ds ops), so global loads ride across 2
// chunks (~600 cyc cover). Buffers are 12 VGPR each (allocator-friendly,
// unlike r7's 48). Everything else identical to r16 (validated).

typedef __attribute__((ext_vector_type(8))) short bf16x8;   // 8 bf16 = 4 VGPR
typedef __attribute__((ext_vector_type(4))) float f32x4;

#define ALPHA 0.0005f
#define TAU 0.2f

#define FDIM 128
#define NGRAM 1024          // gram blocks: 64 sites = 8 chunks of 8
#define NMSE 2048           // mse blocks
#define BLK_FLOATS 24576    // 64 sites * 384 floats
#define NPAIRQ 8192         // packed u32 per partial tile
#define GRAM_ELEMS 16384
#define MSE_N4 2048000      // 8192*1000/4

// branchless RNE f32->bf16 pair pack
__device__ __forceinline__ unsigned int pack_bf2(float lo, float hi) {
    union { float f; unsigned int u; } a, b;
    a.f = lo; b.f = hi;
    unsigned int al = (a.u + 0x7fffu + ((a.u >> 16) & 1u)) >> 16;
    unsigned int bh = (b.u + 0x7fffu + ((b.u >> 16) & 1u)) & 0xffff0000u;
    return (al & 0xffffu) | bh;
}

// fragment: [a.x a.y a.z b.x b.y b.z 0 0] (slots 6,7 zero = exact no-ops;
// same bijection for A and B so the Gram is unchanged). r8/r16-validated.
__device__ __forceinline__ uint4 make_frag(const float3& a, const float3& b) {
    uint4 r;
    r.x = pack_bf2(a.x, a.y);
    r.y = pack_bf2(a.z, b.x);
    r.z = pack_bf2(b.y, b.z);
    r.w = 0;
    return r;
}

__device__ __forceinline__ void load4(const float* __restrict__ p00,
                                      const float* __restrict__ p10,
                                      int c, float3 (&L)[4]) {
    const int co = c * 3072;
    L[0] = *reinterpret_cast<const float3*>(p00 + co);
    L[1] = *reinterpret_cast<const float3*>(p00 + co + 384);
    L[2] = *reinterpret_cast<const float3*>(p10 + co);
    L[3] = *reinterpret_cast<const float3*>(p10 + co + 384);
    __builtin_amdgcn_sched_barrier(0);      // pin loads at issue point
}

// One chunk: consume cur -> frags; prefetch chunk `pre_c` back into the SAME
// buffer (regs already consumed); raw barriers, lgkmcnt-only drains.
__device__ __forceinline__ void gram_chunk(
        const float* __restrict__ p00, const float* __restrict__ p10,
        int pre_c, bool dopre, float3 (&buf)[4],
        uint4 (*fragbuf)[64], int wave, int lane,
        f32x4 (&acc0)[8], f32x4 (&acc1)[8]) {
    const uint4 fA0 = make_frag(buf[0], buf[1]);    // vmcnt wait on buf only
    const uint4 fA1 = make_frag(buf[2], buf[3]);
    if (dopre) load4(p00, p10, pre_c, buf);         // refill, rides barriers
    // drain own ds_reads of previous chunk's fragbuf before it's overwritten
    asm volatile("s_waitcnt lgkmcnt(0)" ::: "memory");
    __builtin_amdgcn_sched_barrier(0);
    __builtin_amdgcn_s_barrier();                   // fragbuf free
    __builtin_amdgcn_sched_barrier(0);
    fragbuf[2 * wave][lane] = fA0;
    fragbuf[2 * wave + 1][lane] = fA1;
    asm volatile("s_waitcnt lgkmcnt(0)" ::: "memory");
    __builtin_amdgcn_sched_barrier(0);
    __builtin_amdgcn_s_barrier();                   // all 8 frags published
    __builtin_amdgcn_sched_barrier(0);
    const bf16x8 va0 = *reinterpret_cast<const bf16x8*>(&fA0);
    const bf16x8 va1 = *reinterpret_cast<const bf16x8*>(&fA1);
#pragma unroll
    for (int cc = 0; cc < 8; ++cc) {
        const uint4 fb = fragbuf[cc][lane];
        const bf16x8 vb = *reinterpret_cast<const bf16x8*>(&fb);
        acc0[cc] = __builtin_amdgcn_mfma_f32_16x16x32_bf16(va0, vb, acc0[cc], 0, 0, 0);
        acc1[cc] = __builtin_amdgcn_mfma_f32_16x16x32_bf16(va1, vb, acc1[cc], 0, 0, 0);
    }
}

// --------------------------------------------- mixed-role fused kernel
// blocks [0, NGRAM): Gram tile partials. [NGRAM, NGRAM+NMSE): MSE.
__global__ void __launch_bounds__(256, 4) fused_kernel(
        const float* __restrict__ o, const float* __restrict__ t,
        const float* __restrict__ conv,
        float* __restrict__ mse_part, unsigned int* __restrict__ pp) {
    __shared__ uint4 fragbuf[8][64];        // 8.2 KB frag exchange
    __shared__ float red[4];
    const int tid = threadIdx.x;
    const int lane = tid & 63;
    const int wave = tid >> 6;

    if (blockIdx.x >= NGRAM) {
        // ---------------- MSE role ----------------
        const int mb = blockIdx.x - NGRAM;
        const int gid = mb * 256 + tid;
        const f32x4* o4 = reinterpret_cast<const f32x4*>(o);
        const f32x4* t4 = reinterpret_cast<const f32x4*>(t);
        float s = 0.f;
        for (int i = gid; i < MSE_N4; i += NMSE * 256) {
            f32x4 a = o4[i], b = t4[i];
            f32x4 d = a - b;
            s += d[0]*d[0] + d[1]*d[1] + d[2]*d[2] + d[3]*d[3];
        }
        for (int off = 32; off; off >>= 1) s += __shfl_down(s, off);
        if (lane == 0) red[wave] = s;
        __syncthreads();
        if (tid == 0) mse_part[mb] = red[0] + red[1] + red[2] + red[3];
        return;
    }

    // ---------------- Gram role ----------------
    // chunk = 8 sites; lane group g -> sites 2g,2g+1 (6 data + 2 zero slots).
    // Wave w produces the 2 fragments for its own rows [32w, 32w+32).
    const int g = lane >> 4;                // lane group 0..3
    const int fl = lane & 15;               // row-within-tile
    const float* bp = conv + (size_t)blockIdx.x * BLK_FLOATS;
    const float* p00 = bp + (2 * g) * 384 + (32 * wave + fl) * 3;
    const float* p10 = p00 + 48;            // rows +16

    f32x4 acc0[8], acc1[8];
#pragma unroll
    for (int cc = 0; cc < 8; ++cc) { acc0[cc] = (f32x4)0.f; acc1[cc] = (f32x4)0.f; }

    float3 LA[4], LB[4];
    load4(p00, p10, 0, LA);
    load4(p00, p10, 1, LB);
#pragma unroll
    for (int c = 0; c < 8; c += 2) {
        gram_chunk(p00, p10, c + 2, c + 2 < 8, LA, fragbuf, wave, lane, acc0, acc1);
        gram_chunk(p00, p10, c + 3, c + 3 < 8, LB, fragbuf, wave, lane, acc0, acc1);
    }

    // epilogue: bf16-pair-packed partial tile (validated layout):
    // u32[pr*128+col] = pack(G[r0], G[r0+16]), pr = wave*16 + rsub + j,
    // r0 = wave*32 + rsub + j, col = cc*16 + colr.
    unsigned int* myp = pp + (size_t)blockIdx.x * NPAIRQ;
    const int colr = lane & 15;
    const int rsub = (lane >> 4) << 2;
#pragma unroll
    for (int cc = 0; cc < 8; ++cc) {
        const int col = cc * 16 + colr;
#pragma unroll
        for (int j = 0; j < 4; ++j) {
            const int pr = wave * 16 + rsub + j;
            myp[pr * FDIM + col] = pack_bf2(acc0[cc][j], acc1[cc][j]);
        }
    }
}

// ------------------------------------------------- partial reduce (bf16 pairs)
// 512 blocks x 256 thr: block owns 16 packed entries; 16 slices of 64 tiles.
// (r12/r16-validated with 1024 tiles)
__global__ void __launch_bounds__(256) reduce_kernel(
        const unsigned int* __restrict__ pp, float* __restrict__ gram) {
    __shared__ float red[16][16][2];
    const int tid = threadIdx.x;
    const int u = tid & 15;
    const int s = tid >> 4;                 // 0..15
    const int qq = blockIdx.x * 16 + u;
    float lo = 0.f, hi = 0.f;
#pragma unroll 8
    for (int b = s * 64; b < s * 64 + 64; ++b) {
        const unsigned int v = pp[(size_t)b * NPAIRQ + qq];
        lo += __uint_as_float(v << 16);
        hi += __uint_as_float(v & 0xffff0000u);
    }
    red[s][u][0] = lo; red[s][u][1] = hi;
    __syncthreads();
    if (tid < 32) {
        const int u2 = tid >> 1, h = tid & 1;
        float x = 0.f;
#pragma unroll
        for (int s2 = 0; s2 < 16; ++s2) x += red[s2][u2][h];
        gram[(blockIdx.x * 16 + u2) * 2 + h] = x;
    }
}

// ------------------------------------------------------------ finalize
// gram layout: g = (pr*128+col)*2 + h, row = (pr>>4)*32 + (pr&15) + 16h
// (r12/r14/r16-validated, 2048 mse entries)
__global__ void __launch_bounds__(256) finalize_kernel(
        const float* __restrict__ gram, const float* __restrict__ mse_part,
        float* __restrict__ out) {
    __shared__ float rn[FDIM];
    __shared__ float redS[4], redM[4];
    const int tid = threadIdx.x;
    if (tid < FDIM) {
        const int row = tid;
        const int pr = (row >> 5) * 16 + (row & 15);
        const int h = (row >> 4) & 1;
        rn[row] = rsqrtf(gram[(pr * FDIM + row) * 2 + h]);
    }
    __syncthreads();
    float s = 0.f;
    for (int i = tid; i < GRAM_ELEMS; i += 256) {
        const int h = i & 1;
        const int qq = i >> 1;
        const int col = qq & 127;
        const int pr = qq >> 7;
        const int row = (pr >> 4) * 32 + (pr & 15) + (h << 4);
        const float gv = gram[i] * rn[row] * rn[col];
        if (row != col && gv > TAU && gv <= 1.0f) s += gv;
    }
    float m = 0.f;
#pragma unroll 8
    for (int j = 0; j < 8; ++j) m += mse_part[tid * 8 + j];   // 2048 entries
    for (int off = 32; off; off >>= 1) {
        s += __shfl_down(s, off);
        m += __shfl_down(m, off);
    }
    if ((tid & 63) == 0) { redS[tid >> 6] = s; redM[tid >> 6] = m; }
    __syncthreads();
    if (tid == 0)
        out[0] = (redM[0] + redM[1] + redM[2] + redM[3]) * (1.0f / 8192000.0f) +
                 ALPHA * (redS[0] + redS[1] + redS[2] + redS[3]);
}

extern "C" void kernel_launch(void* const* d_in, const int* in_sizes, int n_in,
                              void* d_out, int out_size, void* d_ws, size_t ws_size,
                              hipStream_t stream) {
    const float* output = (const float*)d_in[0];
    const float* target = (const float*)d_in[1];
    const float* conv   = (const float*)d_in[2];
    float* out = (float*)d_out;

    float* wsf       = (float*)d_ws;
    float* mse_part  = wsf;                              // 2048 floats
    float* gram      = wsf + NMSE;                       // 16384 floats
    unsigned int* pp = (unsigned int*)(wsf + NMSE + GRAM_ELEMS); // 33.6 MB
    (void)ws_size;   // need ~33.7 MB; harness provides ~402 MB (r5 profile)

    // all buffers fully written before read -> no memsets
    fused_kernel<<<NGRAM + NMSE, 256, 0, stream>>>(output, target, conv,
                                                   mse_part, pp);
    reduce_kernel<<<NPAIRQ / 16, 256, 0, stream>>>(pp, gram);
    finalize_kernel<<<1, 256, 0, stream>>>(gram, mse_part, out);
}